// Round 1
// baseline (345.844 us; speedup 1.0000x reference)
//
#include <hip/hip_runtime.h>
#include <hip/hip_bf16.h>
#include <stdint.h>

#define B_ 2
#define F_ 2
#define C_ 128
#define D_ 96
#define H_ 48
#define W_ 128
#define HW_ (H_*W_)
#define EPS_ 1e-7f
#define DCHUNK 4

__device__ __forceinline__ float bflo(unsigned u){ return __uint_as_float(u << 16); }
__device__ __forceinline__ float bfhi(unsigned u){ return __uint_as_float(u & 0xffff0000u); }

__device__ __forceinline__ float depth_bin(int d){
    // match numpy linspace: f64 arithmetic, cast to f32
    return (float)(0.1 + (double)d * (19.9 / 95.0));
}

// transpose + f32->bf16: src [nslice][C][HW] f32 -> dst [nslice][HW][C] bf16
__global__ void transpose_kernel(const float* __restrict__ src,
                                 __hip_bfloat16* __restrict__ dst){
    __shared__ float tile[32][33];
    const int tx = threadIdx.x & 31, ty = threadIdx.x >> 5;   // ty 0..7
    const int nc = C_ / 32;     // 4
    const int np = HW_ / 32;    // 192
    int bid = blockIdx.x;
    int p0 = (bid % np) * 32;
    int c0 = ((bid / np) % nc) * 32;
    int s  = bid / (np * nc);
    const float* sp = src + (size_t)s * C_ * HW_;
    __hip_bfloat16* dp = dst + (size_t)s * HW_ * C_;
#pragma unroll
    for (int j = 0; j < 4; ++j){
        int c = c0 + ty + j * 8;
        tile[ty + j * 8][tx] = sp[(size_t)c * HW_ + p0 + tx];
    }
    __syncthreads();
#pragma unroll
    for (int j = 0; j < 4; ++j){
        int p = p0 + ty + j * 8;
        dp[(size_t)p * C_ + c0 + tx] = __float2bfloat16(tile[tx][ty + j * 8]);
    }
}

template<bool TR>
__global__ __launch_bounds__(256)
void cost_kernel(const float* __restrict__ cur_f32,
                 const float* __restrict__ look_f32,
                 const float* __restrict__ poses,
                 const float* __restrict__ Kmat,
                 const float* __restrict__ invKm,
                 const __hip_bfloat16* __restrict__ LT,
                 const __hip_bfloat16* __restrict__ CT,
                 float* __restrict__ out_cost)
{
    const int nd = D_ / DCHUNK;                 // 24
    int bid = blockIdx.x;
    int dci = bid % nd;
    int hh  = (bid / nd) % (H_ / 2);
    int b   = bid / (nd * (H_ / 2));
    int w = threadIdx.x & 127;
    int h = hh * 2 + (threadIdx.x >> 7);
    int d0 = dci * DCHUNK;

    float u = (float)w, v = (float)h;
    const float* iK = invKm + b * 16;
    float dirx = iK[0]*u + iK[1]*v + iK[2];
    float diry = iK[4]*u + iK[5]*v + iK[6];
    float dirz = iK[8]*u + iK[9]*v + iK[10];
    const float* Kb = Kmat + b * 16;

    const bool border = (h >= 2 && h <= H_-3 && w >= 2 && w <= W_-3);

    float diffs[F_][DCHUNK];

#pragma unroll
    for (int f = 0; f < F_; ++f){
        const float* ps = poses + ((size_t)b * F_ + f) * 16;
        float psum = 0.f;
#pragma unroll
        for (int i = 0; i < 16; ++i) psum += ps[i];
        const float validf = (psum != 0.0f) ? 1.0f : 0.0f;

        // P = (K @ pose)[:3, :]
        float P[3][4];
#pragma unroll
        for (int i = 0; i < 3; ++i)
#pragma unroll
            for (int j = 0; j < 4; ++j)
                P[i][j] = Kb[i*4+0]*ps[0*4+j] + Kb[i*4+1]*ps[1*4+j]
                        + Kb[i*4+2]*ps[2*4+j] + Kb[i*4+3]*ps[3*4+j];

        float qx = P[0][0]*dirx + P[0][1]*diry + P[0][2]*dirz;
        float qy = P[1][0]*dirx + P[1][1]*diry + P[1][2]*dirz;
        float qz = P[2][0]*dirx + P[2][1]*diry + P[2][2]*dirz;

        int   t00o[DCHUNK], t01o[DCHUNK], t10o[DCHUNK], t11o[DCHUNK];
        float w00[DCHUNK], w01[DCHUNK], w10[DCHUNK], w11[DCHUNK];
        float edgev[DCHUNK];

#pragma unroll
        for (int j = 0; j < DCHUNK; ++j){
            float dv = depth_bin(d0 + j);
            float cz = qz*dv + P[2][3] + EPS_;
            float x = (qx*dv + P[0][3]) / cz;
            float y = (qy*dv + P[1][3]) / cz;
            float x0f = floorf(x), y0f = floorf(y);
            float x1f = x0f + 1.0f, y1f = y0f + 1.0f;
            float wx1 = x - x0f, wx0 = 1.0f - wx1;
            float wy1 = y - y0f, wy0 = 1.0f - wy1;
            bool vx0 = (x0f >= 0.f) && (x0f <= (float)(W_-1));
            bool vx1 = (x1f >= 0.f) && (x1f <= (float)(W_-1));
            bool vy0 = (y0f >= 0.f) && (y0f <= (float)(H_-1));
            bool vy1 = (y1f >= 0.f) && (y1f <= (float)(H_-1));
            int ix0 = (int)fminf(fmaxf(x0f, 0.f), (float)(W_-1));
            int ix1 = (int)fminf(fmaxf(x1f, 0.f), (float)(W_-1));
            int iy0 = (int)fminf(fmaxf(y0f, 0.f), (float)(H_-1));
            int iy1 = (int)fminf(fmaxf(y1f, 0.f), (float)(H_-1));
            w00[j] = (vy0 && vx0) ? wy0*wx0 : 0.f;
            w01[j] = (vy0 && vx1) ? wy0*wx1 : 0.f;
            w10[j] = (vy1 && vx0) ? wy1*wx0 : 0.f;
            w11[j] = (vy1 && vx1) ? wy1*wx1 : 0.f;
            edgev[j] = (border && x >= 2.f && x <= (float)(W_-2)
                               && y >= 2.f && y <= (float)(H_-2)) ? 1.0f : 0.0f;
            if (TR){
                t00o[j] = (iy0*W_ + ix0) * (C_*2);
                t01o[j] = (iy0*W_ + ix1) * (C_*2);
                t10o[j] = (iy1*W_ + ix0) * (C_*2);
                t11o[j] = (iy1*W_ + ix1) * (C_*2);
            } else {
                t00o[j] = iy0*W_ + ix0;
                t01o[j] = iy0*W_ + ix1;
                t10o[j] = iy1*W_ + ix0;
                t11o[j] = iy1*W_ + ix1;
            }
        }

        float acc[DCHUNK] = {0.f, 0.f, 0.f, 0.f};

        if (TR){
            const char* lb = (const char*)LT + ((size_t)(b*F_ + f) * HW_ * C_) * 2;
            const char* cb = (const char*)CT + (((size_t)b * HW_ + h*W_ + w) * C_) * 2;
#pragma unroll 2
            for (int c8 = 0; c8 < C_/8; ++c8){
                uint4 cu = *(const uint4*)(cb + c8*16);
                float cf[8] = {bflo(cu.x), bfhi(cu.x), bflo(cu.y), bfhi(cu.y),
                               bflo(cu.z), bfhi(cu.z), bflo(cu.w), bfhi(cu.w)};
#pragma unroll
                for (int j = 0; j < DCHUNK; ++j){
                    uint4 a  = *(const uint4*)(lb + t00o[j] + c8*16);
                    uint4 bq = *(const uint4*)(lb + t01o[j] + c8*16);
                    uint4 cq = *(const uint4*)(lb + t10o[j] + c8*16);
                    uint4 dq = *(const uint4*)(lb + t11o[j] + c8*16);
                    acc[j] += fabsf(w00[j]*bflo(a.x)+w01[j]*bflo(bq.x)+w10[j]*bflo(cq.x)+w11[j]*bflo(dq.x) - cf[0]);
                    acc[j] += fabsf(w00[j]*bfhi(a.x)+w01[j]*bfhi(bq.x)+w10[j]*bfhi(cq.x)+w11[j]*bfhi(dq.x) - cf[1]);
                    acc[j] += fabsf(w00[j]*bflo(a.y)+w01[j]*bflo(bq.y)+w10[j]*bflo(cq.y)+w11[j]*bflo(dq.y) - cf[2]);
                    acc[j] += fabsf(w00[j]*bfhi(a.y)+w01[j]*bfhi(bq.y)+w10[j]*bfhi(cq.y)+w11[j]*bfhi(dq.y) - cf[3]);
                    acc[j] += fabsf(w00[j]*bflo(a.z)+w01[j]*bflo(bq.z)+w10[j]*bflo(cq.z)+w11[j]*bflo(dq.z) - cf[4]);
                    acc[j] += fabsf(w00[j]*bfhi(a.z)+w01[j]*bfhi(bq.z)+w10[j]*bfhi(cq.z)+w11[j]*bfhi(dq.z) - cf[5]);
                    acc[j] += fabsf(w00[j]*bflo(a.w)+w01[j]*bflo(bq.w)+w10[j]*bflo(cq.w)+w11[j]*bflo(dq.w) - cf[6]);
                    acc[j] += fabsf(w00[j]*bfhi(a.w)+w01[j]*bfhi(bq.w)+w10[j]*bfhi(cq.w)+w11[j]*bfhi(dq.w) - cf[7]);
                }
            }
        } else {
            const float* lb = look_f32 + (size_t)(b*F_ + f) * C_ * HW_;
            const float* cb = cur_f32 + (size_t)b * C_ * HW_ + h*W_ + w;
#pragma unroll 2
            for (int c = 0; c < C_; ++c){
                float cf = cb[(size_t)c * HW_];
                const float* lc = lb + (size_t)c * HW_;
#pragma unroll
                for (int j = 0; j < DCHUNK; ++j){
                    float wv = w00[j]*lc[t00o[j]] + w01[j]*lc[t01o[j]]
                             + w10[j]*lc[t10o[j]] + w11[j]*lc[t11o[j]];
                    acc[j] += fabsf(wv - cf);
                }
            }
        }

#pragma unroll
        for (int j = 0; j < DCHUNK; ++j)
            diffs[f][j] = acc[j] * (1.0f / C_) * edgev[j] * validf;
    }

    size_t ob = ((size_t)b * D_ + d0) * HW_ + h*W_ + w;
#pragma unroll
    for (int j = 0; j < DCHUNK; ++j){
        float df0 = diffs[0][j], df1 = diffs[1][j];
        float cnt = (df0 > 0.f ? 1.f : 0.f) + (df1 > 0.f ? 1.f : 0.f);
        out_cost[ob + (size_t)j * HW_] = (df0 + df1) / (cnt + EPS_);
    }
}

__global__ void finalize_kernel(float* __restrict__ cost, float* __restrict__ missing){
    int t = blockIdx.x * blockDim.x + threadIdx.x;
    if (t >= B_ * HW_) return;
    int b = t / HW_;
    int p = t % HW_;
    float* cp = cost + (size_t)b * D_ * HW_ + p;
    float mx = 0.f;  // cost values are >= 0
    for (int d = 0; d < D_; ++d) mx = fmaxf(mx, cp[(size_t)d * HW_]);
    for (int d = 0; d < D_; ++d){
        float vv = cp[(size_t)d * HW_];
        float miss = (vv == 0.0f) ? 1.0f : 0.0f;
        cp[(size_t)d * HW_] = (vv == 0.0f) ? mx : vv;
        missing[(size_t)b * D_ * HW_ + (size_t)d * HW_ + p] = miss;
    }
}

extern "C" void kernel_launch(void* const* d_in, const int* in_sizes, int n_in,
                              void* d_out, int out_size, void* d_ws, size_t ws_size,
                              hipStream_t stream){
    const float* cur   = (const float*)d_in[0];
    const float* look  = (const float*)d_in[1];
    const float* poses = (const float*)d_in[2];
    const float* Kmat  = (const float*)d_in[3];
    const float* invKm = (const float*)d_in[4];
    float* cost    = (float*)d_out;
    float* missing = cost + (size_t)B_ * D_ * HW_;

    const size_t ltBytes = (size_t)B_ * F_ * HW_ * C_ * 2;
    const size_t ctBytes = (size_t)B_ * HW_ * C_ * 2;
    const bool useTR = (ws_size >= ltBytes + ctBytes);
    const int nblocks = B_ * (H_/2) * (D_/DCHUNK);

    if (useTR){
        __hip_bfloat16* LT = (__hip_bfloat16*)d_ws;
        __hip_bfloat16* CT = (__hip_bfloat16*)((char*)d_ws + ltBytes);
        transpose_kernel<<<(B_*F_)*(C_/32)*(HW_/32), 256, 0, stream>>>(look, LT);
        transpose_kernel<<<B_*(C_/32)*(HW_/32), 256, 0, stream>>>(cur, CT);
        cost_kernel<true><<<nblocks, 256, 0, stream>>>(cur, look, poses, Kmat, invKm, LT, CT, cost);
    } else {
        cost_kernel<false><<<nblocks, 256, 0, stream>>>(cur, look, poses, Kmat, invKm, nullptr, nullptr, cost);
    }
    finalize_kernel<<<(B_*HW_ + 255)/256, 256, 0, stream>>>(cost, missing);
}